// Round 1
// baseline (353.081 us; speedup 1.0000x reference)
//
#include <hip/hip_runtime.h>
#include <stdint.h>

// IterNorm (BWItnBlock): out = Sigma^{-1/2} (x - mean) + beta
// Shapes: X (64,128,56,56) fp32; C=128, m = 64*56*56 = 200704.
// K1: bf16-MFMA Gram partials (256 slots in ws) + channel sums
// K1b: reduce partials -> Sigma (+eps I - mu mu^T), trace
// K2: single-block Newton-Schulz (7 iters, mean-eig normalization; reference's
//     T=10 trace-norm iteration converges to Sigma^{-1/2} to ~1e-8, so any
//     converged Sigma^{-1/2} matches it)
// K3: whitening GEMM, wm & xc in hi/lo bf16 split (near-fp32), +beta
// NOTE: requires ws_size >= ~17 MB (256*16384 partials + small tail)

#define CC    128
#define HWs   3136
#define MM    200704
#define EPSv  1e-5f
#define PITCH 136   // bf16 elements per LDS row for 128-wide matrices (16B-aligned rows, conflict-benign)
#define K1P   72    // LDS pitch for 128x64 staging

typedef __attribute__((ext_vector_type(8))) short  bfrag;
typedef __attribute__((ext_vector_type(4))) short  short4v;
typedef __attribute__((ext_vector_type(4))) float  f32x4;

__device__ __forceinline__ unsigned short f2bf(float x) {
  union { float f; unsigned u; } v; v.f = x;
  unsigned r = (v.u + 0x7FFFu + ((v.u >> 16) & 1u)) >> 16;
  return (unsigned short)r;
}
__device__ __forceinline__ float bf2f(unsigned short h) {
  union { float f; unsigned u; } v; v.u = ((unsigned)h) << 16;
  return v.f;
}

// ---------------- K1: partial Gram + channel sums ----------------
__global__ __launch_bounds__(256) void k1_gram(const float* __restrict__ X,
                                               float* __restrict__ partials,
                                               float* __restrict__ colsum) {
  __shared__ unsigned short Xs[CC * K1P];
  __shared__ float red[256];
  const int t = threadIdx.x;
  const int lane = t & 63;
  const int wave = t >> 6;
  const int m15 = lane & 15;
  const int quad = lane >> 4;
  const int bid = blockIdx.x;          // 256 blocks: (n, quarter)
  const int n = bid >> 2;
  const int qq = bid & 3;
  const int c = t & 127;               // channel row this thread loads
  const int h = t >> 7;                // which 32-sample half
  const float* rowbase = X + ((size_t)(n * CC + c)) * HWs + qq * 784 + h * 32;

  f32x4 acc[2][8];
#pragma unroll
  for (int i = 0; i < 2; ++i)
#pragma unroll
    for (int j = 0; j < 8; ++j) acc[i][j] = (f32x4){0.f, 0.f, 0.f, 0.f};

  float fsum = 0.f;

  for (int ck = 0; ck < 13; ++ck) {   // 13*64 = 832 >= 784, tail zero-padded
    const int s0 = ck * 64;
    float4 vals[8];
#pragma unroll
    for (int u = 0; u < 8; ++u) {
      const int sl = s0 + h * 32 + 4 * u;
      if (sl + 4 <= 784) vals[u] = *(const float4*)(rowbase + s0 + 4 * u);
      else               vals[u] = make_float4(0.f, 0.f, 0.f, 0.f);
    }
    __syncthreads();   // previous chunk's MFMA reads complete
#pragma unroll
    for (int u = 0; u < 8; ++u) {
      fsum += vals[u].x + vals[u].y + vals[u].z + vals[u].w;
      short4v pk;
      pk.x = (short)f2bf(vals[u].x);
      pk.y = (short)f2bf(vals[u].y);
      pk.z = (short)f2bf(vals[u].z);
      pk.w = (short)f2bf(vals[u].w);
      *(short4v*)&Xs[c * K1P + h * 32 + 4 * u] = pk;
    }
    __syncthreads();
#pragma unroll
    for (int kc = 0; kc < 2; ++kc) {
      const int k0 = kc * 32 + quad * 8;
      bfrag a[2], b[8];
#pragma unroll
      for (int i = 0; i < 2; ++i)
        a[i] = *(const bfrag*)&Xs[((wave * 2 + i) * 16 + m15) * K1P + k0];
#pragma unroll
      for (int j = 0; j < 8; ++j)
        b[j] = *(const bfrag*)&Xs[(j * 16 + m15) * K1P + k0];
#pragma unroll
      for (int i = 0; i < 2; ++i)
#pragma unroll
        for (int j = 0; j < 8; ++j)
          acc[i][j] = __builtin_amdgcn_mfma_f32_16x16x32_bf16(a[i], b[j], acc[i][j], 0, 0, 0);
    }
  }

  float* slot = partials + (size_t)bid * 16384;
#pragma unroll
  for (int i = 0; i < 2; ++i)
#pragma unroll
    for (int j = 0; j < 8; ++j)
#pragma unroll
      for (int r = 0; r < 4; ++r) {
        const int row = (wave * 2 + i) * 16 + quad * 4 + r;
        const int col = j * 16 + m15;
        slot[row * 128 + col] = acc[i][j][r];
      }

  __syncthreads();
  red[t] = fsum;
  __syncthreads();
  if (t < 128) atomicAdd(&colsum[t], red[t] + red[t + 128]);
}

// ---------------- K1b: reduce partials -> Sigma, mean, trace ----------------
__global__ __launch_bounds__(256) void k1b_reduce(const float* __restrict__ partials,
                                                  const float* __restrict__ colsum,
                                                  float* __restrict__ Sigma,
                                                  float* __restrict__ meanb,
                                                  float* __restrict__ traceb) {
  const int e = blockIdx.x * 256 + threadIdx.x;   // 64 blocks * 256 = 16384
  float s0 = 0.f, s1 = 0.f, s2 = 0.f, s3 = 0.f;
  for (int p = 0; p < 256; p += 4) {
    s0 += partials[(size_t)(p + 0) * 16384 + e];
    s1 += partials[(size_t)(p + 1) * 16384 + e];
    s2 += partials[(size_t)(p + 2) * 16384 + e];
    s3 += partials[(size_t)(p + 3) * 16384 + e];
  }
  const float s = (s0 + s1) + (s2 + s3);
  const int row = e >> 7, col = e & 127;
  const float inv_m = 1.0f / (float)MM;
  const float mr = colsum[row] * inv_m;
  const float mc = colsum[col] * inv_m;
  float sig = s * inv_m - mr * mc;
  if (row == col) sig += EPSv;
  Sigma[e] = sig;
  if (row == col) atomicAdd(traceb, sig);
  if (e < 128) meanb[e] = colsum[e] * inv_m;
}

// ---------------- K2 helpers ----------------
__device__ __forceinline__ void mmq(f32x4 acc[4][4], const unsigned short* A,
                                    const unsigned short* B, int r0, int c0,
                                    int m15, int quad) {
#pragma unroll
  for (int i = 0; i < 4; ++i)
#pragma unroll
    for (int j = 0; j < 4; ++j) acc[i][j] = (f32x4){0.f, 0.f, 0.f, 0.f};
#pragma unroll
  for (int kc = 0; kc < 4; ++kc) {
    const int k0 = kc * 32 + quad * 8;
    bfrag a[4], b[4];
#pragma unroll
    for (int i = 0; i < 4; ++i)
      a[i] = *(const bfrag*)&A[(r0 + i * 16 + m15) * PITCH + k0];
#pragma unroll
    for (int j = 0; j < 4; ++j)
      b[j] = *(const bfrag*)&B[(c0 + j * 16 + m15) * PITCH + k0];  // B read row-wise: operands symmetric
#pragma unroll
    for (int i = 0; i < 4; ++i)
#pragma unroll
      for (int j = 0; j < 4; ++j)
        acc[i][j] = __builtin_amdgcn_mfma_f32_16x16x32_bf16(a[i], b[j], acc[i][j], 0, 0, 0);
  }
}

__device__ __forceinline__ void storeq(unsigned short* D, f32x4 acc[4][4],
                                       int r0, int c0, int m15, int quad) {
#pragma unroll
  for (int i = 0; i < 4; ++i)
#pragma unroll
    for (int j = 0; j < 4; ++j)
#pragma unroll
      for (int r = 0; r < 4; ++r)
        D[(r0 + i * 16 + quad * 4 + r) * PITCH + c0 + j * 16 + m15] = f2bf(acc[i][j][r]);
}

// ---------------- K2: Newton-Schulz, single block ----------------
__global__ __launch_bounds__(256) void k2_ns(const float* __restrict__ Sigma,
                                             const float* __restrict__ tracep,
                                             float* __restrict__ wm) {
  extern __shared__ unsigned short lds2[];
  unsigned short* P = lds2;
  unsigned short* S = lds2 + 128 * PITCH;
  unsigned short* T = lds2 + 2 * 128 * PITCH;
  const int t = threadIdx.x;
  const int lane = t & 63, wave = t >> 6;
  const int m15 = lane & 15, quad = lane >> 4;
  const float tr = tracep[0];
  const float sc = 128.0f / tr;            // mean-eigenvalue normalization
  for (int e = t; e < 16384; e += 256) {
    const int r = e >> 7, cl = e & 127;
    S[r * PITCH + cl] = f2bf(Sigma[e] * sc);
    P[r * PITCH + cl] = (r == cl) ? (unsigned short)0x3F80 : (unsigned short)0;
  }
  __syncthreads();
  const int r0 = (wave >> 1) * 64, c0 = (wave & 1) * 64;
  f32x4 acc[4][4];
  for (int it = 0; it < 7; ++it) {
    // phase 1: T = P @ P
    mmq(acc, P, P, r0, c0, m15, quad);
    storeq(T, acc, r0, c0, m15, quad);     // only reads of P in flight elsewhere
    __syncthreads();
    // phase 2: T = T @ P   (buffer in regs, then overwrite after all reads done)
    mmq(acc, T, P, r0, c0, m15, quad);
    __syncthreads();
    storeq(T, acc, r0, c0, m15, quad);
    __syncthreads();
    // phase 3: acc = T @ S ; P_new = 1.5 P - 0.5 acc
    mmq(acc, T, S, r0, c0, m15, quad);
    if (it < 6) {
#pragma unroll
      for (int i = 0; i < 4; ++i)
#pragma unroll
        for (int j = 0; j < 4; ++j)
#pragma unroll
          for (int r = 0; r < 4; ++r) {
            const int row = r0 + i * 16 + quad * 4 + r;
            const int col = c0 + j * 16 + m15;
            acc[i][j][r] = 1.5f * bf2f(P[row * PITCH + col]) - 0.5f * acc[i][j][r];
          }
      __syncthreads();
      storeq(P, acc, r0, c0, m15, quad);
      __syncthreads();
    } else {
      const float ks = sqrtf(sc);          // wm = P_final * sqrt(128/tr) = Sigma^{-1/2}
#pragma unroll
      for (int i = 0; i < 4; ++i)
#pragma unroll
        for (int j = 0; j < 4; ++j)
#pragma unroll
          for (int r = 0; r < 4; ++r) {
            const int row = r0 + i * 16 + quad * 4 + r;
            const int col = c0 + j * 16 + m15;
            wm[row * 128 + col] =
                (1.5f * bf2f(P[row * PITCH + col]) - 0.5f * acc[i][j][r]) * ks;
          }
    }
  }
}

// ---------------- K3: whitening GEMM + beta ----------------
__global__ __launch_bounds__(512) void k3_whiten(const float* __restrict__ X,
                                                 const float* __restrict__ wmp,
                                                 const float* __restrict__ meanp,
                                                 const float* __restrict__ beta,
                                                 float* __restrict__ out) {
  extern __shared__ unsigned short lds3[];
  unsigned short* WH = lds3;
  unsigned short* WL = lds3 + 128 * PITCH;
  unsigned short* TH = lds3 + 2 * 128 * PITCH;  // transposed xc tile [sample][channel]
  unsigned short* TL = lds3 + 3 * 128 * PITCH;
  const int t = threadIdx.x;
  const int lane = t & 63, wave = t >> 6;       // 8 waves, wave = output rowtile
  const int m15 = lane & 15, quad = lane >> 4;
  const int c = t & 127, q = t >> 7;            // load mapping: channel, sample-quarter

  for (int e = t; e < 16384; e += 512) {
    const int r = e >> 7, cl = e & 127;
    const float v = wmp[e];
    const unsigned short hh = f2bf(v);
    WH[r * PITCH + cl] = hh;
    WL[r * PITCH + cl] = f2bf(v - bf2f(hh));
  }
  const float mc = meanp[c];
  float bet[4];
#pragma unroll
  for (int r = 0; r < 4; ++r) bet[r] = beta[wave * 16 + quad * 4 + r];
  __syncthreads();

  // wm A-fragments: constant for the whole block -> preload to VGPRs
  bfrag wah[4], wal[4];
#pragma unroll
  for (int kc = 0; kc < 4; ++kc) {
    const int k0 = kc * 32 + quad * 8;
    wah[kc] = *(const bfrag*)&WH[(wave * 16 + m15) * PITCH + k0];
    wal[kc] = *(const bfrag*)&WL[(wave * 16 + m15) * PITCH + k0];
  }

  for (int g = blockIdx.x; g < 1568; g += 256) {   // 1568 tiles of 128 samples
    const int i0 = g * 128;
    const int swin = i0 + 32 * q;                  // 32-sample window (never crosses n: 3136 % 64 == 0)
    const int n = swin / HWs, s = swin % HWs;
    const float* rp = X + ((size_t)(n * CC + c)) * HWs + s;
    float4 vals[8];
#pragma unroll
    for (int u = 0; u < 8; ++u) vals[u] = *(const float4*)(rp + 4 * u);
    __syncthreads();   // previous tile's fragment reads complete
#pragma unroll
    for (int u = 0; u < 8; ++u) {
      const float4 v = vals[u];
      const float xs[4] = {v.x - mc, v.y - mc, v.z - mc, v.w - mc};
#pragma unroll
      for (int e2 = 0; e2 < 4; ++e2) {
        const unsigned short hh = f2bf(xs[e2]);
        const int srow = 32 * q + 4 * u + e2;
        TH[srow * PITCH + c] = hh;
        TL[srow * PITCH + c] = f2bf(xs[e2] - bf2f(hh));
      }
    }
    __syncthreads();
#pragma unroll
    for (int ct = 0; ct < 8; ++ct) {
      f32x4 acc = (f32x4){0.f, 0.f, 0.f, 0.f};
#pragma unroll
      for (int kc = 0; kc < 4; ++kc) {
        const int k0 = kc * 32 + quad * 8;
        const bfrag bh = *(const bfrag*)&TH[(ct * 16 + m15) * PITCH + k0];
        const bfrag bl = *(const bfrag*)&TL[(ct * 16 + m15) * PITCH + k0];
        acc = __builtin_amdgcn_mfma_f32_16x16x32_bf16(wah[kc], bh, acc, 0, 0, 0);
        acc = __builtin_amdgcn_mfma_f32_16x16x32_bf16(wal[kc], bh, acc, 0, 0, 0);
        acc = __builtin_amdgcn_mfma_f32_16x16x32_bf16(wah[kc], bl, acc, 0, 0, 0);
      }
      const int scol = i0 + ct * 16;               // 16-sample group: never crosses n
      const int n2 = scol / HWs, s2 = scol % HWs;
      const int colx = s2 + m15;
#pragma unroll
      for (int r = 0; r < 4; ++r) {
        const int row = wave * 16 + quad * 4 + r;
        out[((size_t)(n2 * CC + row)) * HWs + colx] = acc[r] + bet[r];
      }
    }
  }
}

extern "C" void kernel_launch(void* const* d_in, const int* in_sizes, int n_in,
                              void* d_out, int out_size, void* d_ws, size_t ws_size,
                              hipStream_t stream) {
  const float* X    = (const float*)d_in[0];
  const float* beta = (const float*)d_in[1];
  float* out = (float*)d_out;
  float* ws  = (float*)d_ws;

  float* partials = ws;                                 // 256 * 16384
  float* Sigma    = ws + (size_t)256 * 16384;           // 16384
  float* wmb      = Sigma + 16384;                      // 16384
  float* colsum   = wmb + 16384;                        // 128
  float* meanb    = colsum + 128;                       // 128
  float* traceb   = meanb + 128;                        // 1

  hipMemsetAsync(colsum, 0, (128 + 128 + 1) * sizeof(float), stream);

  k1_gram<<<256, 256, 0, stream>>>(X, partials, colsum);
  k1b_reduce<<<64, 256, 0, stream>>>(partials, colsum, Sigma, meanb, traceb);

  const int lds_k2 = 3 * 128 * PITCH * (int)sizeof(unsigned short);  // 104448 B
  const int lds_k3 = 4 * 128 * PITCH * (int)sizeof(unsigned short);  // 139264 B
  (void)hipFuncSetAttribute((const void*)k2_ns,
                            hipFuncAttributeMaxDynamicSharedMemorySize, lds_k2);
  (void)hipFuncSetAttribute((const void*)k3_whiten,
                            hipFuncAttributeMaxDynamicSharedMemorySize, lds_k3);

  k2_ns<<<1, 256, lds_k2, stream>>>(Sigma, traceb, wmb);
  k3_whiten<<<256, 512, lds_k3, stream>>>(X, wmb, meanb, beta, out);
}

// Round 2
// 297.681 us; speedup vs baseline: 1.1861x; 1.1861x over previous
//
#include <hip/hip_runtime.h>
#include <stdint.h>

// IterNorm (BWItnBlock): out = Sigma^{-1/2} (x - mean) + beta
//   = wm * x + (beta - wm*mu)   <- centering folded into epilogue offset
// K1: bf16-MFMA Gram partials (256 slots in ws) + channel sums (512 thr/blk)
// K1b: reduce partials -> Sigma (+eps I - mu mu^T), trace (128x128)
// K2: single-block Newton-Schulz, 6 iters, mean-eig normalization
// K3: whitening GEMM; wm hi/lo in VGPR frags (staged through ONE reused LDS
//     buffer), x tile bf16-hi only (error ~0.007 abs, threshold 0.109),
//     35 KB LDS -> 2 blocks/CU. Grid-stride over 1568 tiles.

#define CC    128
#define HWs   3136
#define MM    200704
#define EPSv  1e-5f
#define PITCH 136   // bf16 elems per LDS row (16B-aligned rows)
#define K1P   72

typedef __attribute__((ext_vector_type(8))) short  bfrag;
typedef __attribute__((ext_vector_type(4))) short  short4v;
typedef __attribute__((ext_vector_type(4))) float  f32x4;

__device__ __forceinline__ unsigned short f2bf(float x) {
  union { float f; unsigned u; } v; v.f = x;
  unsigned r = (v.u + 0x7FFFu + ((v.u >> 16) & 1u)) >> 16;
  return (unsigned short)r;
}
__device__ __forceinline__ float bf2f(unsigned short h) {
  union { float f; unsigned u; } v; v.u = ((unsigned)h) << 16;
  return v.f;
}

// ---------------- K1: partial Gram + channel sums ----------------
__global__ __launch_bounds__(512, 4) void k1_gram(const float* __restrict__ X,
                                                  float* __restrict__ partials,
                                                  float* __restrict__ colsum) {
  __shared__ unsigned short Xs[CC * K1P];
  __shared__ float red[512];
  const int t = threadIdx.x;
  const int lane = t & 63;
  const int wave = t >> 6;          // 0..7
  const int m15 = lane & 15;
  const int quad = lane >> 4;
  const int bid = blockIdx.x;       // 256 blocks: (n, quarter)
  const int n = bid >> 2;
  const int qq = bid & 3;
  const int c = t & 127;            // channel row this thread loads
  const int q = t >> 7;             // 16-sample slice 0..3
  const float* rowbase = X + ((size_t)(n * CC + c)) * HWs + qq * 784 + q * 16;

  f32x4 acc[8];
#pragma unroll
  for (int j = 0; j < 8; ++j) acc[j] = (f32x4){0.f, 0.f, 0.f, 0.f};
  float fsum = 0.f;

  for (int ck = 0; ck < 13; ++ck) {   // 13*64 = 832 >= 784, tail zero-padded
    const int s0 = ck * 64;
    float4 vals[4];
#pragma unroll
    for (int u = 0; u < 4; ++u) {
      const int sl = s0 + q * 16 + 4 * u;            // wave-uniform guard
      if (sl + 4 <= 784) vals[u] = *(const float4*)(rowbase + s0 + 4 * u);
      else               vals[u] = make_float4(0.f, 0.f, 0.f, 0.f);
    }
    __syncthreads();   // previous chunk's MFMA reads complete
#pragma unroll
    for (int u = 0; u < 4; ++u) {
      fsum += vals[u].x + vals[u].y + vals[u].z + vals[u].w;
      short4v pk;
      pk.x = (short)f2bf(vals[u].x);
      pk.y = (short)f2bf(vals[u].y);
      pk.z = (short)f2bf(vals[u].z);
      pk.w = (short)f2bf(vals[u].w);
      *(short4v*)&Xs[c * K1P + q * 16 + 4 * u] = pk;
    }
    __syncthreads();
#pragma unroll
    for (int kc = 0; kc < 2; ++kc) {
      const int k0 = kc * 32 + quad * 8;
      const bfrag a = *(const bfrag*)&Xs[(wave * 16 + m15) * K1P + k0];
      bfrag b[8];
#pragma unroll
      for (int j = 0; j < 8; ++j)
        b[j] = *(const bfrag*)&Xs[(j * 16 + m15) * K1P + k0];
#pragma unroll
      for (int j = 0; j < 8; ++j)
        acc[j] = __builtin_amdgcn_mfma_f32_16x16x32_bf16(a, b[j], acc[j], 0, 0, 0);
    }
  }

  float* slot = partials + (size_t)bid * 16384;
#pragma unroll
  for (int j = 0; j < 8; ++j)
#pragma unroll
    for (int r = 0; r < 4; ++r) {
      const int row = wave * 16 + quad * 4 + r;
      const int col = j * 16 + m15;
      slot[row * 128 + col] = acc[j][r];
    }

  __syncthreads();
  red[t] = fsum;
  __syncthreads();
  if (t < 128)
    atomicAdd(&colsum[t], red[t] + red[t + 128] + red[t + 256] + red[t + 384]);
}

// ---------------- K1b: reduce partials -> Sigma, mean, trace ----------------
__global__ __launch_bounds__(128) void k1b_reduce(const float* __restrict__ partials,
                                                  const float* __restrict__ colsum,
                                                  float* __restrict__ Sigma,
                                                  float* __restrict__ meanb,
                                                  float* __restrict__ traceb) {
  const int e = blockIdx.x * 128 + threadIdx.x;   // 128 blocks * 128 = 16384
  float s0 = 0.f, s1 = 0.f, s2 = 0.f, s3 = 0.f;
  for (int p = 0; p < 256; p += 4) {
    s0 += partials[(size_t)(p + 0) * 16384 + e];
    s1 += partials[(size_t)(p + 1) * 16384 + e];
    s2 += partials[(size_t)(p + 2) * 16384 + e];
    s3 += partials[(size_t)(p + 3) * 16384 + e];
  }
  const float s = (s0 + s1) + (s2 + s3);
  const int row = e >> 7, col = e & 127;
  const float inv_m = 1.0f / (float)MM;
  const float mr = colsum[row] * inv_m;
  const float mc = colsum[col] * inv_m;
  float sig = s * inv_m - mr * mc;
  if (row == col) sig += EPSv;
  Sigma[e] = sig;
  if (row == col) atomicAdd(traceb, sig);
  if (e < 128) meanb[e] = colsum[e] * inv_m;
}

// ---------------- K2 helpers ----------------
__device__ __forceinline__ void mmq(f32x4 acc[4][4], const unsigned short* A,
                                    const unsigned short* B, int r0, int c0,
                                    int m15, int quad) {
#pragma unroll
  for (int i = 0; i < 4; ++i)
#pragma unroll
    for (int j = 0; j < 4; ++j) acc[i][j] = (f32x4){0.f, 0.f, 0.f, 0.f};
#pragma unroll
  for (int kc = 0; kc < 4; ++kc) {
    const int k0 = kc * 32 + quad * 8;
    bfrag a[4], b[4];
#pragma unroll
    for (int i = 0; i < 4; ++i)
      a[i] = *(const bfrag*)&A[(r0 + i * 16 + m15) * PITCH + k0];
#pragma unroll
    for (int j = 0; j < 4; ++j)
      b[j] = *(const bfrag*)&B[(c0 + j * 16 + m15) * PITCH + k0];  // symmetric operand
#pragma unroll
    for (int i = 0; i < 4; ++i)
#pragma unroll
      for (int j = 0; j < 4; ++j)
        acc[i][j] = __builtin_amdgcn_mfma_f32_16x16x32_bf16(a[i], b[j], acc[i][j], 0, 0, 0);
  }
}

__device__ __forceinline__ void storeq(unsigned short* D, f32x4 acc[4][4],
                                       int r0, int c0, int m15, int quad) {
#pragma unroll
  for (int i = 0; i < 4; ++i)
#pragma unroll
    for (int j = 0; j < 4; ++j)
#pragma unroll
      for (int r = 0; r < 4; ++r)
        D[(r0 + i * 16 + quad * 4 + r) * PITCH + c0 + j * 16 + m15] = f2bf(acc[i][j][r]);
}

// ---------------- K2: Newton-Schulz, single block ----------------
#define NS_ITERS 6
__global__ __launch_bounds__(256) void k2_ns(const float* __restrict__ Sigma,
                                             const float* __restrict__ tracep,
                                             float* __restrict__ wm) {
  extern __shared__ unsigned short lds2[];
  unsigned short* P = lds2;
  unsigned short* S = lds2 + 128 * PITCH;
  unsigned short* T = lds2 + 2 * 128 * PITCH;
  const int t = threadIdx.x;
  const int lane = t & 63, wave = t >> 6;
  const int m15 = lane & 15, quad = lane >> 4;
  const float tr = tracep[0];
  const float sc = 128.0f / tr;            // mean-eigenvalue normalization
  for (int e = t; e < 16384; e += 256) {
    const int r = e >> 7, cl = e & 127;
    S[r * PITCH + cl] = f2bf(Sigma[e] * sc);
    P[r * PITCH + cl] = (r == cl) ? (unsigned short)0x3F80 : (unsigned short)0;
  }
  __syncthreads();
  const int r0 = (wave >> 1) * 64, c0 = (wave & 1) * 64;
  f32x4 acc[4][4];
  for (int it = 0; it < NS_ITERS; ++it) {
    mmq(acc, P, P, r0, c0, m15, quad);       // T = P @ P
    storeq(T, acc, r0, c0, m15, quad);
    __syncthreads();
    mmq(acc, T, P, r0, c0, m15, quad);       // T = T @ P (reg-buffered)
    __syncthreads();
    storeq(T, acc, r0, c0, m15, quad);
    __syncthreads();
    mmq(acc, T, S, r0, c0, m15, quad);       // acc = T @ S ; P = 1.5P - 0.5acc
    if (it < NS_ITERS - 1) {
#pragma unroll
      for (int i = 0; i < 4; ++i)
#pragma unroll
        for (int j = 0; j < 4; ++j)
#pragma unroll
          for (int r = 0; r < 4; ++r) {
            const int row = r0 + i * 16 + quad * 4 + r;
            const int col = c0 + j * 16 + m15;
            acc[i][j][r] = 1.5f * bf2f(P[row * PITCH + col]) - 0.5f * acc[i][j][r];
          }
      __syncthreads();
      storeq(P, acc, r0, c0, m15, quad);
      __syncthreads();
    } else {
      const float ks = sqrtf(sc);            // wm = P_final * sqrt(128/tr)
#pragma unroll
      for (int i = 0; i < 4; ++i)
#pragma unroll
        for (int j = 0; j < 4; ++j)
#pragma unroll
          for (int r = 0; r < 4; ++r) {
            const int row = r0 + i * 16 + quad * 4 + r;
            const int col = c0 + j * 16 + m15;
            wm[row * 128 + col] =
                (1.5f * bf2f(P[row * PITCH + col]) - 0.5f * acc[i][j][r]) * ks;
          }
    }
  }
}

// ---------------- K3: whitening GEMM + folded epilogue ----------------
__global__ __launch_bounds__(512, 4) void k3_whiten(const float* __restrict__ X,
                                                    const float* __restrict__ wmp,
                                                    const float* __restrict__ meanp,
                                                    const float* __restrict__ beta,
                                                    float* __restrict__ out) {
  extern __shared__ unsigned short lds3[];
  unsigned short* TH = lds3;                        // 128 x PITCH, triple-reused
  float* offs = (float*)(lds3 + 128 * PITCH);       // 128 floats: beta - wm*mu
  const int t = threadIdx.x;
  const int lane = t & 63, wave = t >> 6;           // 8 waves = 8 output rowtiles
  const int m15 = lane & 15, quad = lane >> 4;
  const int c = t & 127, q = t >> 7;                // loader: channel, 32-sample slice

  // phase A: stage wm-hi, grab A-frags, compute offs
  for (int e = t; e < 16384; e += 512) {
    const int r = e >> 7, cl = e & 127;
    TH[r * PITCH + cl] = f2bf(wmp[e]);
  }
  __syncthreads();
  bfrag wah[4], wal[4];
#pragma unroll
  for (int kc = 0; kc < 4; ++kc)
    wah[kc] = *(const bfrag*)&TH[(wave * 16 + m15) * PITCH + kc * 32 + quad * 8];
  if (t < 128) {
    float o = 0.f;
    for (int d = 0; d < 128; ++d) o += bf2f(TH[t * PITCH + d]) * meanp[d];
    offs[t] = beta[t] - o;
  }
  __syncthreads();
  // phase B: stage wm-lo in the SAME buffer, grab lo A-frags
  for (int e = t; e < 16384; e += 512) {
    const int r = e >> 7, cl = e & 127;
    const float v = wmp[e];
    TH[r * PITCH + cl] = f2bf(v - bf2f(f2bf(v)));
  }
  __syncthreads();
#pragma unroll
  for (int kc = 0; kc < 4; ++kc)
    wal[kc] = *(const bfrag*)&TH[(wave * 16 + m15) * PITCH + kc * 32 + quad * 8];
  float bet[4];
#pragma unroll
  for (int r = 0; r < 4; ++r) bet[r] = offs[wave * 16 + quad * 4 + r];
  __syncthreads();

  // phase C: grid-stride tiles of 128 samples; TH now holds x^T tile (hi only)
  for (int g = blockIdx.x; g < 1568; g += 512) {
    const int i0 = g * 128;
    const int swin = i0 + 32 * q;                  // never crosses n (3136%128==0)
    const int n = swin / HWs, s = swin % HWs;
    const float* rp = X + ((size_t)(n * CC + c)) * HWs + s;
    float4 vals[8];
#pragma unroll
    for (int u = 0; u < 8; ++u) vals[u] = *(const float4*)(rp + 4 * u);
    __syncthreads();   // previous tile's fragment reads complete
#pragma unroll
    for (int u = 0; u < 8; ++u) {
      const float4 v = vals[u];
      const int srow = 32 * q + 4 * u;
      TH[(srow + 0) * PITCH + c] = f2bf(v.x);
      TH[(srow + 1) * PITCH + c] = f2bf(v.y);
      TH[(srow + 2) * PITCH + c] = f2bf(v.z);
      TH[(srow + 3) * PITCH + c] = f2bf(v.w);
    }
    __syncthreads();
#pragma unroll
    for (int ct = 0; ct < 8; ++ct) {
      f32x4 acc = (f32x4){0.f, 0.f, 0.f, 0.f};
#pragma unroll
      for (int kc = 0; kc < 4; ++kc) {
        const bfrag bh = *(const bfrag*)&TH[(ct * 16 + m15) * PITCH + kc * 32 + quad * 8];
        acc = __builtin_amdgcn_mfma_f32_16x16x32_bf16(wah[kc], bh, acc, 0, 0, 0);
        acc = __builtin_amdgcn_mfma_f32_16x16x32_bf16(wal[kc], bh, acc, 0, 0, 0);
      }
      const int scol = i0 + ct * 16;               // 16-sample group within one n
      const int n2 = scol / HWs, s2 = scol % HWs;
      const int colx = s2 + m15;
#pragma unroll
      for (int r = 0; r < 4; ++r) {
        const int row = wave * 16 + quad * 4 + r;
        out[((size_t)(n2 * CC + row)) * HWs + colx] = acc[r] + bet[r];
      }
    }
  }
}

extern "C" void kernel_launch(void* const* d_in, const int* in_sizes, int n_in,
                              void* d_out, int out_size, void* d_ws, size_t ws_size,
                              hipStream_t stream) {
  const float* X    = (const float*)d_in[0];
  const float* beta = (const float*)d_in[1];
  float* out = (float*)d_out;
  float* ws  = (float*)d_ws;

  float* partials = ws;                                 // 256 * 16384
  float* Sigma    = ws + (size_t)256 * 16384;           // 16384
  float* wmb      = Sigma + 16384;                      // 16384
  float* colsum   = wmb + 16384;                        // 128
  float* meanb    = colsum + 128;                       // 128
  float* traceb   = meanb + 128;                        // 1

  hipMemsetAsync(colsum, 0, (128 + 128 + 1) * sizeof(float), stream);

  k1_gram<<<256, 512, 0, stream>>>(X, partials, colsum);
  k1b_reduce<<<128, 128, 0, stream>>>(partials, colsum, Sigma, meanb, traceb);

  const int lds_k2 = 3 * 128 * PITCH * (int)sizeof(unsigned short);  // 104448 B
  const int lds_k3 = 128 * PITCH * (int)sizeof(unsigned short) + 128 * (int)sizeof(float);
  (void)hipFuncSetAttribute((const void*)k2_ns,
                            hipFuncAttributeMaxDynamicSharedMemorySize, lds_k2);
  (void)hipFuncSetAttribute((const void*)k3_whiten,
                            hipFuncAttributeMaxDynamicSharedMemorySize, lds_k3);

  k2_ns<<<1, 256, lds_k2, stream>>>(Sigma, traceb, wmb);
  k3_whiten<<<512, 512, lds_k3, stream>>>(X, wmb, meanb, beta, out);
}